// Round 6
// baseline (468.297 us; speedup 1.0000x reference)
//
#include <hip/hip_runtime.h>
#include <hip/hip_bf16.h>
#include <math.h>

// Problem constants (fixed by the reference).
#define Bn 4
#define Sn 2048
#define En 1024
#define Hn 16
#define Dn 64
#define Mn (Bn * Sn)  // 8192 rows in the flattened GEMMs

typedef __attribute__((ext_vector_type(8))) short short8;
typedef __attribute__((ext_vector_type(4))) short short4v;
typedef __attribute__((ext_vector_type(16))) float f32x16;

#if __has_builtin(__builtin_amdgcn_exp2f)
#define EXP2(x) __builtin_amdgcn_exp2f(x)
#else
#define EXP2(x) exp2f(x)
#endif

__device__ inline unsigned short f2bf(float f) {  // round-to-nearest-even bf16
    unsigned int u = __float_as_uint(f);
    u += 0x7FFFu + ((u >> 16) & 1u);
    return (unsigned short)(u >> 16);
}
__device__ inline float bf2f(unsigned short h) {
    return __uint_as_float(((unsigned int)h) << 16);
}
__device__ inline void split2(float f, unsigned short& hi, unsigned short& lo) {
    hi = f2bf(f);
    lo = f2bf(f - bf2f(hi));
}
__device__ inline short8 ld8s(const unsigned short* p) {  // LDS, 8B-aligned
    union { short4v h[2]; short8 v; } r;
    r.h[0] = *(const short4v*)p;
    r.h[1] = *(const short4v*)(p + 4);
    return r.v;
}
__device__ inline short8 g8(const unsigned short* p) {  // global, 16B-aligned
    union { int4 i; short8 v; } r;
    r.i = *(const int4*)p;
    return r.v;
}

// ---------------------------------------------------------------------------
// RoPE cos/sin table, fp64-accurate: [S][32] each.
// ---------------------------------------------------------------------------
__global__ void rope_table_kernel(float* __restrict__ ct, float* __restrict__ st) {
    int i = blockIdx.x * blockDim.x + threadIdx.x;
    if (i < Sn * 32) {
        int s = i >> 5, p = i & 31;
        double inv = pow(10000.0, -(double)p / 32.0);
        double a = (double)s * inv;
        ct[i] = (float)cos(a);
        st[i] = (float)sin(a);
    }
}

// ---------------------------------------------------------------------------
// X fp32 -> bf16 (hi only). 4 elts/thread.
// ---------------------------------------------------------------------------
__global__ __launch_bounds__(256) void convx_kernel(
    const float* __restrict__ X, unsigned short* __restrict__ Xh) {
    int i = blockIdx.x * 256 + threadIdx.x;
    float4 v = ((const float4*)X)[i];
    float f[4] = {v.x, v.y, v.z, v.w};
    short4v h;
#pragma unroll
    for (int j = 0; j < 4; ++j) h[j] = (short)f2bf(f[j]);
    ((short4v*)Xh)[i] = h;
}

// ---------------------------------------------------------------------------
// W fp32 [K][N] -> transposed bf16 [N][K]. 64x64 tile via LDS.
// ---------------------------------------------------------------------------
__global__ __launch_bounds__(256) void tconv_kernel(
    const float* __restrict__ W, unsigned short* __restrict__ WhT) {
    __shared__ float Ws[64][65];
    const int t = threadIdx.x;
    const int kb = blockIdx.y * 64, nb = blockIdx.x * 64;
    const int lr = t >> 2, lc = (t & 3) * 16;
#pragma unroll
    for (int u = 0; u < 4; ++u) {
        float4 v = *(const float4*)&W[(size_t)(kb + lr) * En + nb + lc + 4 * u];
        Ws[lr][lc + 4 * u + 0] = v.x; Ws[lr][lc + 4 * u + 1] = v.y;
        Ws[lr][lc + 4 * u + 2] = v.z; Ws[lr][lc + 4 * u + 3] = v.w;
    }
    __syncthreads();
    const int orow = t >> 2, ock = (t & 3) * 16;
#pragma unroll
    for (int u = 0; u < 4; ++u) {
        short4v hs;
#pragma unroll
        for (int j = 0; j < 4; ++j) hs[j] = (short)f2bf(Ws[ock + 4 * u + j][orow]);
        *(short4v*)&WhT[(size_t)(nb + orow) * En + kb + ock + 4 * u] = hs;
    }
}

// ---------------------------------------------------------------------------
// V [B,H,S,D] bf16 -> V^T [B,H,D,S] bf16. 64x64 tile via LDS, so attention's
// V staging becomes a straight 16B copy (no in-kernel transpose VALU).
// ---------------------------------------------------------------------------
__global__ __launch_bounds__(256) void vtrans_kernel(
    const unsigned short* __restrict__ Vb, unsigned short* __restrict__ VbT) {
    __shared__ unsigned short Ts[64][68];  // 34-word stride: 2-way (free)
    const int t = threadIdx.x;
    const int bh = blockIdx.y;
    const int s0 = blockIdx.x * 64;
    const size_t ibase = (size_t)bh * Sn * Dn;
    const int lr = t >> 2, lc = (t & 3) * 16;
    int4 i0 = *(const int4*)&Vb[ibase + (size_t)(s0 + lr) * Dn + lc];
    int4 i1 = *(const int4*)&Vb[ibase + (size_t)(s0 + lr) * Dn + lc + 8];
    *(int2*)&Ts[lr][lc] = make_int2(i0.x, i0.y);
    *(int2*)&Ts[lr][lc + 4] = make_int2(i0.z, i0.w);
    *(int2*)&Ts[lr][lc + 8] = make_int2(i1.x, i1.y);
    *(int2*)&Ts[lr][lc + 12] = make_int2(i1.z, i1.w);
    __syncthreads();
    const int dr = t >> 2, sc = (t & 3) * 16;
    unsigned short o[16];
#pragma unroll
    for (int j = 0; j < 16; ++j) o[j] = Ts[sc + j][dr];
    unsigned short* op = &VbT[(size_t)bh * Dn * Sn + (size_t)dr * Sn + s0 + sc];
    *(int4*)&op[0] = *(int4*)&o[0];
    *(int4*)&op[8] = *(int4*)&o[8];
}

// ---------------------------------------------------------------------------
// Fused QKV MFMA GEMM (1-term bf16). B = concatenated [3072][1024] W^T
// (rows 0-1023 Wq, 1024-2047 Wk, 2048-3071 Wv). Pipeline per k-step:
// stores(LDS) -> barrier -> PREFETCH next k into regs -> compute. The
// prefetched regs are consumed by next iter's stores, so the vmcnt drain
// at the barrier finds an empty queue (latency hidden by compute).
// Epilogue mode by matrix id: 0=Q (RoPE*0.125*log2e), 1=K (RoPE), 2=V.
// C/D layout (32x32): col = lane&31, row = (reg&3)+8*(reg>>2)+4*(lane>>5).
// ---------------------------------------------------------------------------
__global__ __launch_bounds__(256) void qkv_gemm(
    const unsigned short* __restrict__ Xh, const unsigned short* __restrict__ WT,
    const float* __restrict__ bq, const float* __restrict__ bk,
    const float* __restrict__ bv,
    unsigned short* __restrict__ Qb, unsigned short* __restrict__ Kb,
    unsigned short* __restrict__ Vb,
    const float* __restrict__ ct, const float* __restrict__ st) {
    __shared__ unsigned short As[2][128][36];
    __shared__ unsigned short Bs[2][128][36];
    const int t = threadIdx.x;
    const int w = t >> 6, l = t & 63, h2 = l >> 5, ln = l & 31;
    const int wm = w & 1, wn = w >> 1;
    const int m0 = blockIdx.y * 128, n0 = blockIdx.x * 128;
    const int sr = t >> 2, sc = (t & 3) * 8;

    f32x16 acc[2][2];
#pragma unroll
    for (int i = 0; i < 2; ++i)
#pragma unroll
        for (int j = 0; j < 2; ++j)
#pragma unroll
            for (int r = 0; r < 16; ++r) acc[i][j][r] = 0.0f;

    const unsigned short* Ap0 = &Xh[(size_t)(m0 + sr) * En + sc];
    const unsigned short* Ap1 = Ap0 + (size_t)64 * En;
    const unsigned short* Bp0 = &WT[(size_t)(n0 + sr) * En + sc];
    const unsigned short* Bp1 = Bp0 + (size_t)64 * En;

    int4 a0 = *(const int4*)Ap0, a1 = *(const int4*)Ap1;
    int4 b0 = *(const int4*)Bp0, b1 = *(const int4*)Bp1;

#pragma unroll 2
    for (int k0 = 0; k0 < En; k0 += 32) {
        const int pb = (k0 >> 5) & 1;
        *(int2*)&As[pb][sr][sc] = make_int2(a0.x, a0.y);
        *(int2*)&As[pb][sr][sc + 4] = make_int2(a0.z, a0.w);
        *(int2*)&As[pb][sr + 64][sc] = make_int2(a1.x, a1.y);
        *(int2*)&As[pb][sr + 64][sc + 4] = make_int2(a1.z, a1.w);
        *(int2*)&Bs[pb][sr][sc] = make_int2(b0.x, b0.y);
        *(int2*)&Bs[pb][sr][sc + 4] = make_int2(b0.z, b0.w);
        *(int2*)&Bs[pb][sr + 64][sc] = make_int2(b1.x, b1.y);
        *(int2*)&Bs[pb][sr + 64][sc + 4] = make_int2(b1.z, b1.w);
        __syncthreads();
        const int kn = (k0 + 32) & (En - 1);  // last iter wraps (harmless)
        a0 = *(const int4*)(Ap0 + kn);
        a1 = *(const int4*)(Ap1 + kn);
        b0 = *(const int4*)(Bp0 + kn);
        b1 = *(const int4*)(Bp1 + kn);
#pragma unroll
        for (int s = 0; s < 2; ++s) {
            const int ko = 16 * s + 8 * h2;
            short8 ah0 = ld8s(&As[pb][64 * wm + ln][ko]);
            short8 ah1 = ld8s(&As[pb][64 * wm + 32 + ln][ko]);
            short8 bh0 = ld8s(&Bs[pb][64 * wn + ln][ko]);
            short8 bh1 = ld8s(&Bs[pb][64 * wn + 32 + ln][ko]);
            acc[0][0] = __builtin_amdgcn_mfma_f32_32x32x16_bf16(ah0, bh0, acc[0][0], 0, 0, 0);
            acc[0][1] = __builtin_amdgcn_mfma_f32_32x32x16_bf16(ah0, bh1, acc[0][1], 0, 0, 0);
            acc[1][0] = __builtin_amdgcn_mfma_f32_32x32x16_bf16(ah1, bh0, acc[1][0], 0, 0, 0);
            acc[1][1] = __builtin_amdgcn_mfma_f32_32x32x16_bf16(ah1, bh1, acc[1][1], 0, 0, 0);
        }
    }

    const int mat = n0 >> 10;                 // 0=Q, 1=K, 2=V
    const int nbl = (n0 & 1023) + 64 * wn;    // col within the matrix
    const int hh = nbl >> 6;
    const float* bs = (mat == 0) ? bq : (mat == 1) ? bk : bv;
    unsigned short* op = (mat == 0) ? Qb : (mat == 1) ? Kb : Vb;
#pragma unroll
    for (int i = 0; i < 2; ++i) {
#pragma unroll
        for (int r = 0; r < 16; ++r) {
            const int row = (r & 3) + 8 * (r >> 2) + 4 * h2;
            const int m = m0 + 64 * wm + 32 * i + row;
            const int b = m >> 11, s2 = m & (Sn - 1);
            const size_t base = (((size_t)(b * Hn + hh)) * Sn + s2) * Dn;
            float v0 = acc[i][0][r] + bs[nbl + ln];
            float v1 = acc[i][1][r] + bs[nbl + 32 + ln];
            if (mat <= 1) {  // RoPE for Q and K
                float c = ct[s2 * 32 + ln], sn = st[s2 * 32 + ln];
                float o0 = v0 * c - v1 * sn;
                float o1 = v1 * c + v0 * sn;
                if (mat == 0) {
                    o0 *= 0.18033688011112042f;  // D^-0.5 * log2(e)
                    o1 *= 0.18033688011112042f;
                }
                v0 = o0; v1 = o1;
            }
            op[base + ln] = f2bf(v0);
            op[base + 32 + ln] = f2bf(v1);
        }
    }
}

// ---------------------------------------------------------------------------
// Final projection GEMM, 2-term (Ah.Bh + Al.Bh + bias), fp32 out. Same
// pipelined structure as qkv_gemm.
// ---------------------------------------------------------------------------
__global__ __launch_bounds__(256) void out_gemm(
    const unsigned short* __restrict__ Ah, const unsigned short* __restrict__ Al,
    const unsigned short* __restrict__ BhT, const float* __restrict__ bias,
    float* __restrict__ outF) {
    __shared__ unsigned short As[2][128][36];
    __shared__ unsigned short AsL[2][128][36];
    __shared__ unsigned short Bs[2][128][36];
    const int t = threadIdx.x;
    const int w = t >> 6, l = t & 63, h2 = l >> 5, ln = l & 31;
    const int wm = w & 1, wn = w >> 1;
    const int m0 = blockIdx.y * 128, n0 = blockIdx.x * 128;
    const int sr = t >> 2, sc = (t & 3) * 8;

    f32x16 acc[2][2];
#pragma unroll
    for (int i = 0; i < 2; ++i)
#pragma unroll
        for (int j = 0; j < 2; ++j)
#pragma unroll
            for (int r = 0; r < 16; ++r) acc[i][j][r] = 0.0f;

    const unsigned short* Ap0 = &Ah[(size_t)(m0 + sr) * En + sc];
    const unsigned short* Ap1 = Ap0 + (size_t)64 * En;
    const unsigned short* Lp0 = &Al[(size_t)(m0 + sr) * En + sc];
    const unsigned short* Lp1 = Lp0 + (size_t)64 * En;
    const unsigned short* Bp0 = &BhT[(size_t)(n0 + sr) * En + sc];
    const unsigned short* Bp1 = Bp0 + (size_t)64 * En;

    int4 a0 = *(const int4*)Ap0, a1 = *(const int4*)Ap1;
    int4 c0 = *(const int4*)Lp0, c1 = *(const int4*)Lp1;
    int4 b0 = *(const int4*)Bp0, b1 = *(const int4*)Bp1;

#pragma unroll 2
    for (int k0 = 0; k0 < En; k0 += 32) {
        const int pb = (k0 >> 5) & 1;
        *(int2*)&As[pb][sr][sc] = make_int2(a0.x, a0.y);
        *(int2*)&As[pb][sr][sc + 4] = make_int2(a0.z, a0.w);
        *(int2*)&As[pb][sr + 64][sc] = make_int2(a1.x, a1.y);
        *(int2*)&As[pb][sr + 64][sc + 4] = make_int2(a1.z, a1.w);
        *(int2*)&AsL[pb][sr][sc] = make_int2(c0.x, c0.y);
        *(int2*)&AsL[pb][sr][sc + 4] = make_int2(c0.z, c0.w);
        *(int2*)&AsL[pb][sr + 64][sc] = make_int2(c1.x, c1.y);
        *(int2*)&AsL[pb][sr + 64][sc + 4] = make_int2(c1.z, c1.w);
        *(int2*)&Bs[pb][sr][sc] = make_int2(b0.x, b0.y);
        *(int2*)&Bs[pb][sr][sc + 4] = make_int2(b0.z, b0.w);
        *(int2*)&Bs[pb][sr + 64][sc] = make_int2(b1.x, b1.y);
        *(int2*)&Bs[pb][sr + 64][sc + 4] = make_int2(b1.z, b1.w);
        __syncthreads();
        const int kn = (k0 + 32) & (En - 1);
        a0 = *(const int4*)(Ap0 + kn);
        a1 = *(const int4*)(Ap1 + kn);
        c0 = *(const int4*)(Lp0 + kn);
        c1 = *(const int4*)(Lp1 + kn);
        b0 = *(const int4*)(Bp0 + kn);
        b1 = *(const int4*)(Bp1 + kn);
#pragma unroll
        for (int s = 0; s < 2; ++s) {
            const int ko = 16 * s + 8 * h2;
            short8 ah0 = ld8s(&As[pb][64 * wm + ln][ko]);
            short8 ah1 = ld8s(&As[pb][64 * wm + 32 + ln][ko]);
            short8 al0 = ld8s(&AsL[pb][64 * wm + ln][ko]);
            short8 al1 = ld8s(&AsL[pb][64 * wm + 32 + ln][ko]);
            short8 bh0 = ld8s(&Bs[pb][64 * wn + ln][ko]);
            short8 bh1 = ld8s(&Bs[pb][64 * wn + 32 + ln][ko]);
            acc[0][0] = __builtin_amdgcn_mfma_f32_32x32x16_bf16(ah0, bh0, acc[0][0], 0, 0, 0);
            acc[0][1] = __builtin_amdgcn_mfma_f32_32x32x16_bf16(ah0, bh1, acc[0][1], 0, 0, 0);
            acc[1][0] = __builtin_amdgcn_mfma_f32_32x32x16_bf16(ah1, bh0, acc[1][0], 0, 0, 0);
            acc[1][1] = __builtin_amdgcn_mfma_f32_32x32x16_bf16(ah1, bh1, acc[1][1], 0, 0, 0);
            acc[0][0] = __builtin_amdgcn_mfma_f32_32x32x16_bf16(al0, bh0, acc[0][0], 0, 0, 0);
            acc[0][1] = __builtin_amdgcn_mfma_f32_32x32x16_bf16(al0, bh1, acc[0][1], 0, 0, 0);
            acc[1][0] = __builtin_amdgcn_mfma_f32_32x32x16_bf16(al1, bh0, acc[1][0], 0, 0, 0);
            acc[1][1] = __builtin_amdgcn_mfma_f32_32x32x16_bf16(al1, bh1, acc[1][1], 0, 0, 0);
        }
    }

    const int nb = n0 + 64 * wn;
#pragma unroll
    for (int i = 0; i < 2; ++i) {
#pragma unroll
        for (int r = 0; r < 16; ++r) {
            const int row = (r & 3) + 8 * (r >> 2) + 4 * h2;
            const int m = m0 + 64 * wm + 32 * i + row;
            outF[(size_t)m * En + nb + ln] = acc[i][0][r] + bias[nb + ln];
            outF[(size_t)m * En + nb + 32 + ln] = acc[i][1][r] + bias[nb + 32 + ln];
        }
    }
}

// ---------------------------------------------------------------------------
// MFMA flash attention, pipelined. Per 32-key tile: stage K [key][d] and
// V^T [d][key] (pre-transposed globally -> pure 16B copies) into
// double-buffered LDS; ONE barrier; then PREFETCH the next tile's K/V/mask
// into registers (in flight during compute, consumed by next iter's stores
// -> barrier drain finds empty vmem queue). Mask folded into QK acc init.
// Max-free softmax p = exp2(s) (scale folded into Q), P truncated to bf16
// (numerator/denominator share truncation). O written hi/lo bf16 [B,S,H,D].
// ---------------------------------------------------------------------------
__global__ __launch_bounds__(256) void attn_mfma_kernel(
    const unsigned short* __restrict__ Qb, const unsigned short* __restrict__ Kb,
    const unsigned short* __restrict__ VbT, const unsigned char* __restrict__ mask,
    unsigned short* __restrict__ Oh, unsigned short* __restrict__ Ol) {
    __shared__ unsigned short Ks[2][32][76];  // [key][d], 38-word stride: 2-way
    __shared__ unsigned short Vs[2][64][36];  // [d][key], 18-word stride: 2-way
    __shared__ unsigned short Ps[128][36];    // P bf16, C->A relayout (wave-private)

    const int t = threadIdx.x;
    const int w = t >> 6, l = t & 63, h2 = l >> 5, ln = l & 31;
    const int q0 = blockIdx.x * 128;
    const int h = blockIdx.y, b = blockIdx.z;
    const size_t ho = ((size_t)(b * Hn + h)) * Sn * Dn;
    const unsigned char* maskB = mask + (size_t)b * Sn;

    // Q fragments (A-layout, pre-scaled), loaded once
    short8 qh[4];
    const int qrow = q0 + 32 * w + ln;
#pragma unroll
    for (int s = 0; s < 4; ++s)
        qh[s] = g8(&Qb[ho + (size_t)qrow * Dn + 16 * s + 8 * h2]);

    f32x16 accO0, accO1;
#pragma unroll
    for (int i = 0; i < 16; ++i) { accO0[i] = 0.0f; accO1[i] = 0.0f; }
    float lpart[16] = {};

    const int kr = t >> 3, kc = (t & 7) * 8;  // K staging: key row, d offset
    const int vr = t >> 2, vc = (t & 3) * 8;  // V staging: d row, key offset
    const unsigned short* Kp = &Kb[ho + (size_t)kr * Dn + kc];
    const unsigned short* Vp = &VbT[ho + (size_t)vr * Sn + vc];

    // prologue: prefetch tile 0
    int4 ck = *(const int4*)Kp;
    int4 cv = *(const int4*)Vp;
    unsigned char cm = maskB[ln];

#pragma unroll 2
    for (int kt = 0; kt < Sn / 32; ++kt) {
        const int pb = kt & 1;
        *(int2*)&Ks[pb][kr][kc] = make_int2(ck.x, ck.y);
        *(int2*)&Ks[pb][kr][kc + 4] = make_int2(ck.z, ck.w);
        *(int2*)&Vs[pb][vr][vc] = make_int2(cv.x, cv.y);
        *(int2*)&Vs[pb][vr][vc + 4] = make_int2(cv.z, cv.w);
        const float mb = cm ? -1.0e30f : 0.0f;
        __syncthreads();
        // prefetch tile kt+1 (wraps on last iter; harmless)
        const int kn = ((kt + 1) & (Sn / 32 - 1)) * 32;
        ck = *(const int4*)(Kp + (size_t)kn * Dn);
        cv = *(const int4*)(Vp + kn);
        cm = maskB[kn + ln];

        // QK^T: 32x32 per wave, acc seeded with mask bias (col == lane)
        f32x16 accS;
#pragma unroll
        for (int i = 0; i < 16; ++i) accS[i] = mb;
#pragma unroll
        for (int s = 0; s < 4; ++s) {
            short8 kf = ld8s(&Ks[pb][ln][16 * s + 8 * h2]);
            accS = __builtin_amdgcn_mfma_f32_32x32x16_bf16(qh[s], kf, accS, 0, 0, 0);
        }

        // softmax (max-free): p = 2^s, truncate to bf16; P -> LDS
#pragma unroll
        for (int r = 0; r < 16; ++r) {
            float p = EXP2(accS[r]);
            unsigned int u = __float_as_uint(p);
            lpart[r] += __uint_as_float(u & 0xFFFF0000u);
            const int row = (r & 3) + 8 * (r >> 2) + 4 * h2;
            Ps[32 * w + row][ln] = (unsigned short)(u >> 16);
        }
        // P rows are wave-private: intra-wave lgkmcnt ordering suffices.

        // PV: A = P (bf16), B = Vs (V^T tile)
#pragma unroll
        for (int s = 0; s < 2; ++s) {
            short8 pf = ld8s(&Ps[32 * w + ln][16 * s + 8 * h2]);
            short8 v0 = ld8s(&Vs[pb][ln][16 * s + 8 * h2]);
            short8 v1 = ld8s(&Vs[pb][32 + ln][16 * s + 8 * h2]);
            accO0 = __builtin_amdgcn_mfma_f32_32x32x16_bf16(pf, v0, accO0, 0, 0, 0);
            accO1 = __builtin_amdgcn_mfma_f32_32x32x16_bf16(pf, v1, accO1, 0, 0, 0);
        }
    }

    // reduce row sums (each physical row lives in one 32-lane half), store
#pragma unroll
    for (int r = 0; r < 16; ++r) {
#pragma unroll
        for (int d = 1; d <= 16; d <<= 1) lpart[r] += __shfl_xor(lpart[r], d);
        lpart[r] = 1.0f / fmaxf(lpart[r], 1e-37f);
    }
#pragma unroll
    for (int r = 0; r < 16; ++r) {
        const int row = (r & 3) + 8 * (r >> 2) + 4 * h2;
        const int s = q0 + 32 * w + row;
        const size_t base = (((size_t)b * Sn + s) * Hn + h) * Dn;  // [B,S,H,D]
        unsigned short a, b2;
        split2(accO0[r] * lpart[r], a, b2);
        Oh[base + ln] = a; Ol[base + ln] = b2;
        split2(accO1[r] * lpart[r], a, b2);
        Oh[base + 32 + ln] = a; Ol[base + 32 + ln] = b2;
    }
}

// ---------------------------------------------------------------------------
// Workspace (shorts unless noted):
//   Xh | Ol | Qb | Kb | Vb | VbT | WqkvT(3x) | WohT | ct st (float)
// Attention Oh aliases Xh (X dead after QKV GEMM; same stream).
// ---------------------------------------------------------------------------
extern "C" void kernel_launch(void* const* d_in, const int* in_sizes, int n_in,
                              void* d_out, int out_size, void* d_ws, size_t ws_size,
                              hipStream_t stream) {
    const float* x  = (const float*)d_in[0];
    const float* Wq = (const float*)d_in[1];
    const float* bq = (const float*)d_in[2];
    const float* Wk = (const float*)d_in[3];
    const float* bk = (const float*)d_in[4];
    const float* Wv = (const float*)d_in[5];
    const float* bv = (const float*)d_in[6];
    const float* Wo = (const float*)d_in[7];
    const float* bo = (const float*)d_in[8];
    const unsigned char* mask = (const unsigned char*)d_in[9];

    const size_t NE = (size_t)Mn * En;  // 8,388,608
    const size_t WN = (size_t)En * En;  // 1,048,576
    unsigned short* ws = (unsigned short*)d_ws;
    unsigned short* Xh = ws;
    unsigned short* Ol = Xh + NE;
    unsigned short* Qb = Ol + NE;
    unsigned short* Kb = Qb + NE;
    unsigned short* Vb = Kb + NE;
    unsigned short* VbT = Vb + NE;
    unsigned short* WqkvT = VbT + NE;   // 3 * WN
    unsigned short* WohT = WqkvT + 3 * WN;
    float* ct = (float*)(WohT + WN);
    float* st = ct + (size_t)Sn * 32;
    unsigned short* Oh = Xh;  // alias: X consumed before attention runs

    rope_table_kernel<<<(Sn * 32 + 255) / 256, 256, 0, stream>>>(ct, st);
    convx_kernel<<<(int)(NE / 1024), 256, 0, stream>>>(x, Xh);
    dim3 tg(16, 16);
    tconv_kernel<<<tg, 256, 0, stream>>>(Wq, WqkvT);
    tconv_kernel<<<tg, 256, 0, stream>>>(Wk, WqkvT + WN);
    tconv_kernel<<<tg, 256, 0, stream>>>(Wv, WqkvT + 2 * WN);
    tconv_kernel<<<tg, 256, 0, stream>>>(Wo, WohT);

    qkv_gemm<<<dim3(3 * En / 128, Mn / 128), 256, 0, stream>>>(
        Xh, WqkvT, bq, bk, bv, Qb, Kb, Vb, ct, st);

    vtrans_kernel<<<dim3(Sn / 64, Bn * Hn), 256, 0, stream>>>(Vb, VbT);

    attn_mfma_kernel<<<dim3(Sn / 128, Hn, Bn), 256, 0, stream>>>(
        Qb, Kb, VbT, mask, Oh, Ol);

    out_gemm<<<dim3(En / 128, Mn / 128), 256, 0, stream>>>(
        Oh, Ol, WohT, bo, (float*)d_out);
}

// Round 7
// 377.867 us; speedup vs baseline: 1.2393x; 1.2393x over previous
//
#include <hip/hip_runtime.h>
#include <hip/hip_bf16.h>
#include <math.h>

// Problem constants (fixed by the reference).
#define Bn 4
#define Sn 2048
#define En 1024
#define Hn 16
#define Dn 64
#define Mn (Bn * Sn)  // 8192 rows in the flattened GEMMs

typedef __attribute__((ext_vector_type(8))) short short8;
typedef __attribute__((ext_vector_type(4))) short short4v;
typedef __attribute__((ext_vector_type(4))) float f32x4;
typedef __attribute__((ext_vector_type(16))) float f32x16;

#if __has_builtin(__builtin_amdgcn_exp2f)
#define EXP2(x) __builtin_amdgcn_exp2f(x)
#else
#define EXP2(x) exp2f(x)
#endif

// async global->LDS, 16 B per lane; LDS dest = wave-uniform base + lane*16
#define GLOAD16(g, s) __builtin_amdgcn_global_load_lds( \
    (const __attribute__((address_space(1))) unsigned int*)(g), \
    (__attribute__((address_space(3))) unsigned int*)(s), 16, 0, 0)

__device__ inline unsigned short f2bf(float f) {  // round-to-nearest-even bf16
    unsigned int u = __float_as_uint(f);
    u += 0x7FFFu + ((u >> 16) & 1u);
    return (unsigned short)(u >> 16);
}
__device__ inline float bf2f(unsigned short h) {
    return __uint_as_float(((unsigned int)h) << 16);
}
__device__ inline void split2(float f, unsigned short& hi, unsigned short& lo) {
    hi = f2bf(f);
    lo = f2bf(f - bf2f(hi));
}
__device__ inline short8 ld8s(const unsigned short* p) {  // LDS, 16B-aligned
    union { short4v h[2]; short8 v; } r;
    r.h[0] = *(const short4v*)p;
    r.h[1] = *(const short4v*)(p + 4);
    return r.v;
}
__device__ inline short8 g8(const unsigned short* p) {  // global, 16B-aligned
    union { int4 i; short8 v; } r;
    r.i = *(const int4*)p;
    return r.v;
}

// ---------------------------------------------------------------------------
// RoPE cos/sin table, fp64-accurate: [S][32] each.
// ---------------------------------------------------------------------------
__global__ void rope_table_kernel(float* __restrict__ ct, float* __restrict__ st) {
    int i = blockIdx.x * blockDim.x + threadIdx.x;
    if (i < Sn * 32) {
        int s = i >> 5, p = i & 31;
        double inv = pow(10000.0, -(double)p / 32.0);
        double a = (double)s * inv;
        ct[i] = (float)cos(a);
        st[i] = (float)sin(a);
    }
}

// ---------------------------------------------------------------------------
// X fp32 -> bf16 (hi only). 4 elts/thread.
// ---------------------------------------------------------------------------
__global__ __launch_bounds__(256) void convx_kernel(
    const float* __restrict__ X, unsigned short* __restrict__ Xh) {
    int i = blockIdx.x * 256 + threadIdx.x;
    float4 v = ((const float4*)X)[i];
    float f[4] = {v.x, v.y, v.z, v.w};
    short4v h;
#pragma unroll
    for (int j = 0; j < 4; ++j) h[j] = (short)f2bf(f[j]);
    ((short4v*)Xh)[i] = h;
}

// ---------------------------------------------------------------------------
// W fp32 [K][N] -> transposed bf16 [N][K-rowLen]; optional duplicate copy at
// column offset 1024 (K-doubling for the 2-term output GEMM).
// ---------------------------------------------------------------------------
__global__ __launch_bounds__(256) void tconv_kernel(
    const float* __restrict__ W, unsigned short* __restrict__ WhT,
    int rowLen, int dup) {
    __shared__ float Ws[64][65];
    const int t = threadIdx.x;
    const int kb = blockIdx.y * 64, nb = blockIdx.x * 64;
    const int lr = t >> 2, lc = (t & 3) * 16;
#pragma unroll
    for (int u = 0; u < 4; ++u) {
        float4 v = *(const float4*)&W[(size_t)(kb + lr) * En + nb + lc + 4 * u];
        Ws[lr][lc + 4 * u + 0] = v.x; Ws[lr][lc + 4 * u + 1] = v.y;
        Ws[lr][lc + 4 * u + 2] = v.z; Ws[lr][lc + 4 * u + 3] = v.w;
    }
    __syncthreads();
    const int orow = t >> 2, ock = (t & 3) * 16;
#pragma unroll
    for (int u = 0; u < 4; ++u) {
        short4v hs;
#pragma unroll
        for (int j = 0; j < 4; ++j) hs[j] = (short)f2bf(Ws[ock + 4 * u + j][orow]);
        unsigned short* dst = &WhT[(size_t)(nb + orow) * rowLen + kb + ock + 4 * u];
        *(short4v*)dst = hs;
        if (dup) *(short4v*)(dst + 1024) = hs;
    }
}

// ---------------------------------------------------------------------------
// V [B,H,S,D] bf16 -> V^T [B,H,D,S] bf16. 64x64 tile via LDS.
// ---------------------------------------------------------------------------
__global__ __launch_bounds__(256) void vtrans_kernel(
    const unsigned short* __restrict__ Vb, unsigned short* __restrict__ VbT) {
    __shared__ unsigned short Ts[64][68];  // 34-word stride: 2-way (free)
    const int t = threadIdx.x;
    const int bh = blockIdx.y;
    const int s0 = blockIdx.x * 64;
    const size_t ibase = (size_t)bh * Sn * Dn;
    const int lr = t >> 2, lc = (t & 3) * 16;
    int4 i0 = *(const int4*)&Vb[ibase + (size_t)(s0 + lr) * Dn + lc];
    int4 i1 = *(const int4*)&Vb[ibase + (size_t)(s0 + lr) * Dn + lc + 8];
    *(int2*)&Ts[lr][lc] = make_int2(i0.x, i0.y);
    *(int2*)&Ts[lr][lc + 4] = make_int2(i0.z, i0.w);
    *(int2*)&Ts[lr][lc + 8] = make_int2(i1.x, i1.y);
    *(int2*)&Ts[lr][lc + 12] = make_int2(i1.z, i1.w);
    __syncthreads();
    const int dr = t >> 2, sc = (t & 3) * 16;
    unsigned short o[16];
#pragma unroll
    for (int j = 0; j < 16; ++j) o[j] = Ts[sc + j][dr];
    unsigned short* op = &VbT[(size_t)bh * Dn * Sn + (size_t)dr * Sn + s0 + sc];
    *(int4*)&op[0] = *(int4*)&o[0];
    *(int4*)&op[8] = *(int4*)&o[8];
}

// ---------------------------------------------------------------------------
// m97-recipe MFMA GEMM (HW-verified structure: 874-912 TF at 4096^3).
// C[M][N] = A[M][KN] . Bt[N][KN]^T. 128x128 tile, 4 waves, each 64x64 as
// 4x4 of 16x16x32 bf16 MFMA. Staging via global_load_lds width=16 into
// UNPADDED As/Bs[128][64] (wave-uniform base + lane*16 scatter). Per K-iter:
// 8 global_load_lds + 16 ds_read_b128 + 32 MFMA per wave, 2 barriers.
// C/D (16x16): col = lane&15, row = (lane>>4)*4 + reg.
// EPI 0: fp32 out [M][En] + bias b0   (final projection)
// EPI 1: fused QKV epilogue; matrix by n0>>10 (0=Q RoPE*scale, 1=K RoPE, 2=V),
//        bf16 out [B,H,S,D].
// ---------------------------------------------------------------------------
template <int KN, int EPI>
__global__ __launch_bounds__(256) void gemm97(
    const unsigned short* __restrict__ A, const unsigned short* __restrict__ Bt,
    const float* __restrict__ b0, const float* __restrict__ bkv,
    const float* __restrict__ bvv,
    unsigned short* __restrict__ oQ, unsigned short* __restrict__ oK,
    unsigned short* __restrict__ oV, float* __restrict__ oF,
    const float* __restrict__ ct, const float* __restrict__ st) {
    __shared__ unsigned short As[128][64];
    __shared__ unsigned short Bs[128][64];
    const int t = threadIdx.x;
    const int w = t >> 6, l = t & 63;
    const int wm = w & 1, wn = w >> 1;
    const int q = l >> 4, ln16 = l & 15;  // quad, lane-in-16
    const int r8 = l >> 3, i8 = l & 7;    // staging: row-in-8, 16B chunk
    const int m0 = blockIdx.y * 128, n0 = blockIdx.x * 128;

    f32x4 acc[4][4];
#pragma unroll
    for (int i = 0; i < 4; ++i)
#pragma unroll
        for (int j = 0; j < 4; ++j)
#pragma unroll
            for (int r = 0; r < 4; ++r) acc[i][j][r] = 0.0f;

    // wave w stages rows 32w..32w+31 of both tiles; lane -> (8j+r8, 8*i8)
    const unsigned short* Ag = &A[(size_t)(m0 + 32 * w + r8) * KN + 8 * i8];
    const unsigned short* Bg = &Bt[(size_t)(n0 + 32 * w + r8) * KN + 8 * i8];

    for (int k0 = 0; k0 < KN; k0 += 64) {
        __syncthreads();  // prev iter's ds_reads done before overwrite
#pragma unroll
        for (int j = 0; j < 4; ++j) {
            GLOAD16(Ag + (size_t)(8 * j) * KN + k0, &As[32 * w + 8 * j][0]);
            GLOAD16(Bg + (size_t)(8 * j) * KN + k0, &Bs[32 * w + 8 * j][0]);
        }
        __syncthreads();  // compiler drains vmcnt before this barrier
#pragma unroll
        for (int ks = 0; ks < 2; ++ks) {
            short8 af[4], bf[4];
#pragma unroll
            for (int i = 0; i < 4; ++i)
                af[i] = ld8s(&As[64 * wm + 16 * i + ln16][32 * ks + 8 * q]);
#pragma unroll
            for (int j = 0; j < 4; ++j)
                bf[j] = ld8s(&Bs[64 * wn + 16 * j + ln16][32 * ks + 8 * q]);
#pragma unroll
            for (int i = 0; i < 4; ++i)
#pragma unroll
                for (int j = 0; j < 4; ++j)
                    acc[i][j] = __builtin_amdgcn_mfma_f32_16x16x32_bf16(
                        af[i], bf[j], acc[i][j], 0, 0, 0);
        }
    }

    if (EPI == 0) {
#pragma unroll
        for (int i = 0; i < 4; ++i)
#pragma unroll
            for (int r = 0; r < 4; ++r) {
                const int m = m0 + 64 * wm + 16 * i + 4 * q + r;
#pragma unroll
                for (int j = 0; j < 4; ++j) {
                    const int n = n0 + 64 * wn + 16 * j + ln16;
                    oF[(size_t)m * En + n] = acc[i][j][r] + b0[n];
                }
            }
    } else {
        const int mat = n0 >> 10;               // 0=Q, 1=K, 2=V
        const int nIn = (n0 & 1023) + 64 * wn;  // 64-aligned col in matrix
        const int hh = nIn >> 6;                // head
        const float* bias = (mat == 0) ? b0 : (mat == 1) ? bkv : bvv;
        unsigned short* op = (mat == 0) ? oQ : (mat == 1) ? oK : oV;
#pragma unroll
        for (int i = 0; i < 4; ++i)
#pragma unroll
            for (int r = 0; r < 4; ++r) {
                const int m = m0 + 64 * wm + 16 * i + 4 * q + r;
                const int b = m >> 11, s2 = m & (Sn - 1);
                const size_t base = (((size_t)(b * Hn + hh)) * Sn + s2) * Dn;
#pragma unroll
                for (int j = 0; j < 2; ++j) {  // RoPE pairs: tiles j and j+2
                    const int nh = 16 * j + ln16;  // 0..31 == freq idx
                    float v0 = acc[i][j][r] + bias[nIn + nh];
                    float v1 = acc[i][j + 2][r] + bias[nIn + nh + 32];
                    if (mat <= 1) {
                        float c = ct[s2 * 32 + nh], sn = st[s2 * 32 + nh];
                        float o0 = v0 * c - v1 * sn;
                        float o1 = v1 * c + v0 * sn;
                        if (mat == 0) {
                            o0 *= 0.18033688011112042f;  // D^-0.5 * log2(e)
                            o1 *= 0.18033688011112042f;
                        }
                        v0 = o0; v1 = o1;
                    }
                    op[base + nh] = f2bf(v0);
                    op[base + nh + 32] = f2bf(v1);
                }
            }
    }
}

// ---------------------------------------------------------------------------
// MFMA flash attention (round-5/6 structure, kept). O is written into an
// interleaved [Mn][2048] buffer: hi bf16 at cols 0..1023 ([S,H,D] order),
// lo bf16 at cols 1024..2047 -- consumed by the K=2048 output GEMM.
// ---------------------------------------------------------------------------
__global__ __launch_bounds__(256) void attn_mfma_kernel(
    const unsigned short* __restrict__ Qb, const unsigned short* __restrict__ Kb,
    const unsigned short* __restrict__ VbT, const unsigned char* __restrict__ mask,
    unsigned short* __restrict__ Obuf) {
    __shared__ unsigned short Ks[2][32][76];  // [key][d], 38-word stride: 2-way
    __shared__ unsigned short Vs[2][64][36];  // [d][key], 18-word stride: 2-way
    __shared__ unsigned short Ps[128][36];    // P bf16, C->A relayout (wave-private)

    const int t = threadIdx.x;
    const int w = t >> 6, l = t & 63, h2 = l >> 5, ln = l & 31;
    const int q0 = blockIdx.x * 128;
    const int h = blockIdx.y, b = blockIdx.z;
    const size_t ho = ((size_t)(b * Hn + h)) * Sn * Dn;
    const unsigned char* maskB = mask + (size_t)b * Sn;

    short8 qh[4];
    const int qrow = q0 + 32 * w + ln;
#pragma unroll
    for (int s = 0; s < 4; ++s)
        qh[s] = g8(&Qb[ho + (size_t)qrow * Dn + 16 * s + 8 * h2]);

    f32x16 accO0, accO1;
#pragma unroll
    for (int i = 0; i < 16; ++i) { accO0[i] = 0.0f; accO1[i] = 0.0f; }
    float lpart[16] = {};

    const int kr = t >> 3, kc = (t & 7) * 8;  // K staging: key row, d offset
    const int vr = t >> 2, vc = (t & 3) * 8;  // V staging: d row, key offset
    const unsigned short* Kp = &Kb[ho + (size_t)kr * Dn + kc];
    const unsigned short* Vp = &VbT[ho + (size_t)vr * Sn + vc];

    int4 ck = *(const int4*)Kp;
    int4 cv = *(const int4*)Vp;
    unsigned char cm = maskB[ln];

#pragma unroll 2
    for (int kt = 0; kt < Sn / 32; ++kt) {
        const int pb = kt & 1;
        *(int2*)&Ks[pb][kr][kc] = make_int2(ck.x, ck.y);
        *(int2*)&Ks[pb][kr][kc + 4] = make_int2(ck.z, ck.w);
        *(int2*)&Vs[pb][vr][vc] = make_int2(cv.x, cv.y);
        *(int2*)&Vs[pb][vr][vc + 4] = make_int2(cv.z, cv.w);
        const float mb = cm ? -1.0e30f : 0.0f;
        __syncthreads();
        const int kn = ((kt + 1) & (Sn / 32 - 1)) * 32;  // prefetch (wraps)
        ck = *(const int4*)(Kp + (size_t)kn * Dn);
        cv = *(const int4*)(Vp + kn);
        cm = maskB[kn + ln];

        f32x16 accS;
#pragma unroll
        for (int i = 0; i < 16; ++i) accS[i] = mb;
#pragma unroll
        for (int s = 0; s < 4; ++s) {
            short8 kf = ld8s(&Ks[pb][ln][16 * s + 8 * h2]);
            accS = __builtin_amdgcn_mfma_f32_32x32x16_bf16(qh[s], kf, accS, 0, 0, 0);
        }

#pragma unroll
        for (int r = 0; r < 16; ++r) {
            float p = EXP2(accS[r]);
            unsigned int u = __float_as_uint(p);
            lpart[r] += __uint_as_float(u & 0xFFFF0000u);
            const int row = (r & 3) + 8 * (r >> 2) + 4 * h2;
            Ps[32 * w + row][ln] = (unsigned short)(u >> 16);
        }

#pragma unroll
        for (int s = 0; s < 2; ++s) {
            short8 pf = ld8s(&Ps[32 * w + ln][16 * s + 8 * h2]);
            short8 v0 = ld8s(&Vs[pb][ln][16 * s + 8 * h2]);
            short8 v1 = ld8s(&Vs[pb][32 + ln][16 * s + 8 * h2]);
            accO0 = __builtin_amdgcn_mfma_f32_32x32x16_bf16(pf, v0, accO0, 0, 0, 0);
            accO1 = __builtin_amdgcn_mfma_f32_32x32x16_bf16(pf, v1, accO1, 0, 0, 0);
        }
    }

#pragma unroll
    for (int r = 0; r < 16; ++r) {
#pragma unroll
        for (int d = 1; d <= 16; d <<= 1) lpart[r] += __shfl_xor(lpart[r], d);
        lpart[r] = 1.0f / fmaxf(lpart[r], 1e-37f);
    }
#pragma unroll
    for (int r = 0; r < 16; ++r) {
        const int row = (r & 3) + 8 * (r >> 2) + 4 * h2;
        const int s = q0 + 32 * w + row;
        const size_t base = ((size_t)b * Sn + s) * 2048 + h * Dn;  // [M][2048]
        unsigned short a, b2;
        split2(accO0[r] * lpart[r], a, b2);
        Obuf[base + ln] = a; Obuf[base + 1024 + ln] = b2;
        split2(accO1[r] * lpart[r], a, b2);
        Obuf[base + 32 + ln] = a; Obuf[base + 1024 + 32 + ln] = b2;
    }
}

// ---------------------------------------------------------------------------
// Workspace (shorts unless noted):
//   Xh | Qb | Kb | Vb | VbT | Obuf(2*NE) | WqkvT(3*WN) | WoT2(2*WN) | ct st
// ---------------------------------------------------------------------------
extern "C" void kernel_launch(void* const* d_in, const int* in_sizes, int n_in,
                              void* d_out, int out_size, void* d_ws, size_t ws_size,
                              hipStream_t stream) {
    const float* x  = (const float*)d_in[0];
    const float* Wq = (const float*)d_in[1];
    const float* bq = (const float*)d_in[2];
    const float* Wk = (const float*)d_in[3];
    const float* bk = (const float*)d_in[4];
    const float* Wv = (const float*)d_in[5];
    const float* bv = (const float*)d_in[6];
    const float* Wo = (const float*)d_in[7];
    const float* bo = (const float*)d_in[8];
    const unsigned char* mask = (const unsigned char*)d_in[9];

    const size_t NE = (size_t)Mn * En;  // 8,388,608
    const size_t WN = (size_t)En * En;  // 1,048,576
    unsigned short* ws = (unsigned short*)d_ws;
    unsigned short* Xh = ws;
    unsigned short* Qb = Xh + NE;
    unsigned short* Kb = Qb + NE;
    unsigned short* Vb = Kb + NE;
    unsigned short* VbT = Vb + NE;
    unsigned short* Obuf = VbT + NE;      // 2 * NE (hi | lo interleaved cols)
    unsigned short* WqkvT = Obuf + 2 * NE;  // 3 * WN
    unsigned short* WoT2 = WqkvT + 3 * WN;  // 2 * WN (duplicated K halves)
    float* ct = (float*)(WoT2 + 2 * WN);
    float* st = ct + (size_t)Sn * 32;

    rope_table_kernel<<<(Sn * 32 + 255) / 256, 256, 0, stream>>>(ct, st);
    convx_kernel<<<(int)(NE / 1024), 256, 0, stream>>>(x, Xh);
    dim3 tg(16, 16);
    tconv_kernel<<<tg, 256, 0, stream>>>(Wq, WqkvT, En, 0);
    tconv_kernel<<<tg, 256, 0, stream>>>(Wk, WqkvT + WN, En, 0);
    tconv_kernel<<<tg, 256, 0, stream>>>(Wv, WqkvT + 2 * WN, En, 0);
    tconv_kernel<<<tg, 256, 0, stream>>>(Wo, WoT2, 2048, 1);

    gemm97<En, 1><<<dim3(3 * En / 128, Mn / 128), 256, 0, stream>>>(
        Xh, WqkvT, bq, bk, bv, Qb, Kb, Vb, nullptr, ct, st);

    vtrans_kernel<<<dim3(Sn / 64, Bn * Hn), 256, 0, stream>>>(Vb, VbT);

    attn_mfma_kernel<<<dim3(Sn / 128, Hn, Bn), 256, 0, stream>>>(
        Qb, Kb, VbT, mask, Obuf);

    gemm97<2048, 0><<<dim3(En / 128, Mn / 128), 256, 0, stream>>>(
        Obuf, WoT2, bo, nullptr, nullptr, nullptr, nullptr, nullptr,
        (float*)d_out, ct, st);
}